// Round 6
// baseline (1310.482 us; speedup 1.0000x reference)
//
#include <hip/hip_runtime.h>
#include <stdint.h>

#define B 64
#define T 100
#define IN_F 700
#define RED 256
#define WID 4096
#define CLS 20
#define BT (B*T)                   // 6400
#define NELEM (BT*WID)             // 26,214,400
#define LOGITS_OFF 0
#define SPIKES_OFF (B*CLS)         // 1280
#define DRIVE_OFF (SPIKES_OFF + NELEM)

typedef float v4f __attribute__((ext_vector_type(4)));

// ---- ws layout (floats) ----
#define WS_SLOTS 0                            // 3 u32
#define WS_W2Q 16                             // 20*4096
#define WS_XP  (WS_W2Q + CLS*WID)             // 6400*256
#define WS_CO  (WS_XP + BT*RED)               // 6400*256
#define WS_WEIGHTED (WS_CO + BT*RED)          // 64*4096

// ---- scratch inside d_out's spikes region (consumed before spikes written) ----
#define SC_WST 0                              // 700*256   transposed q4(spatial_W)
#define SC_W1T (SC_WST + IN_F*RED)            // 256*4096  transposed q4(fc1_W)
#define SC_CWT (SC_W1T + RED*WID)             // 1280*256  conv_W as [h][ic][o]
#define SC_IM2 (SC_CWT + 1280*256)            // 6400*1280 im2col of xp

__host__ __device__ __forceinline__ uint32_t rotl32(uint32_t v, int r) {
  return (v << r) | (v >> (32 - r));
}

// JAX threefry2x32 (20 rounds), bit-exact.
__host__ __device__ __forceinline__ void threefry2x32(uint32_t k0, uint32_t k1,
                                                      uint32_t x0, uint32_t x1,
                                                      uint32_t& o0, uint32_t& o1) {
  uint32_t k2 = k0 ^ k1 ^ 0x1BD11BDAu;
  x0 += k0; x1 += k1;
#define TF_R(r) { x0 += x1; x1 = rotl32(x1, (r)); x1 ^= x0; }
  TF_R(13) TF_R(15) TF_R(26) TF_R(6)
  x0 += k1; x1 += k2 + 1u;
  TF_R(17) TF_R(29) TF_R(16) TF_R(24)
  x0 += k2; x1 += k0 + 2u;
  TF_R(13) TF_R(15) TF_R(26) TF_R(6)
  x0 += k0; x1 += k1 + 3u;
  TF_R(17) TF_R(29) TF_R(16) TF_R(24)
  x0 += k1; x1 += k2 + 4u;
  TF_R(13) TF_R(15) TF_R(26) TF_R(6)
  x0 += k2; x1 += k0 + 5u;
#undef TF_R
  o0 = x0; o1 = x1;
}

__global__ void absmax_kernel(const float* __restrict__ w, int n, uint32_t* slot) {
  __shared__ uint32_t sm[256];
  uint32_t m = 0u;
  for (int i = blockIdx.x * 256 + threadIdx.x; i < n; i += gridDim.x * 256)
    m = max(m, __float_as_uint(fabsf(w[i])));
  sm[threadIdx.x] = m;
  __syncthreads();
  for (int s = 128; s > 0; s >>= 1) {
    if (threadIdx.x < s) sm[threadIdx.x] = max(sm[threadIdx.x], sm[threadIdx.x + s]);
    __syncthreads();
  }
  if (threadIdx.x == 0) atomicMax(slot, sm[0]);
}

// LDS tiled transpose + quantize: w[Nn][Kk] -> qT[Kk][Nn], both sides coalesced.
__global__ void quant_t_kernel(const float* __restrict__ w, float* __restrict__ qT,
                               int Nn, int Kk, const uint32_t* __restrict__ slot) {
  __shared__ float tile[32][33];
  float s = fmaxf(__uint_as_float(*slot) / 7.0f, 1e-8f);
  int k0 = blockIdx.x * 32, n0 = blockIdx.y * 32;
  int xx = threadIdx.x & 31, y = threadIdx.x >> 5;   // y in 0..7
#pragma unroll
  for (int p = 0; p < 4; ++p) {
    int n = n0 + y + p * 8, k = k0 + xx;
    if (n < Nn && k < Kk) tile[y + p * 8][xx] = w[(size_t)n * Kk + k];
  }
  __syncthreads();
#pragma unroll
  for (int p = 0; p < 4; ++p) {
    int k = k0 + y + p * 8, n = n0 + xx;
    if (k < Kk && n < Nn)
      qT[(size_t)k * Nn + n] = rintf(tile[xx][y + p * 8] / s) * s;
  }
}

__global__ void quant_kernel(const float* __restrict__ w, float* __restrict__ q,
                             int n, const uint32_t* __restrict__ slot) {
  float s = fmaxf(__uint_as_float(*slot) / 7.0f, 1e-8f);
  int i = blockIdx.x * 256 + threadIdx.x;
  if (i < n) q[i] = rintf(w[i] / s) * s;
}

// conv_W [o][ic][h] -> [h*256+ic][o]
__global__ void convw_t_kernel(const float* __restrict__ w, float* __restrict__ wt) {
  int id = blockIdx.x * 256 + threadIdx.x;   // < 256*1280
  if (id < 256 * 1280) {
    int o = id / 1280, r = id - o * 1280;
    int ic = r / 5, h = r - ic * 5;
    wt[(size_t)((h << 8) + ic) * 256 + o] = w[id];
  }
}

// im2col: A2[bt][h*256+ic] = xp[b][t+h-2][ic] (zero pad)
__global__ void im2col_kernel(const float* __restrict__ xp, float* __restrict__ A2) {
  int id = blockIdx.x * 256 + threadIdx.x;   // < 6400*1280
  int bt = id / 1280;
  int k = id - bt * 1280;
  int h = k >> 8, ic = k & 255;
  int b = bt / T, t = bt - b * T;
  int tt = t + h - 2;
  float v = 0.f;
  if (tt >= 0 && tt < T) v = xp[((size_t)(b * T + tt)) * RED + ic];
  __builtin_nontemporal_store(v, &A2[id]);
}

// Tiled GEMM: C[m][n] = epi( sum_k A[m][k]*Bt[k][n] + bias[n] )
// Per-element: fmaf chain, k ascending from 0 -> bit-identical to verified order.
// mode 0: xcd-stripe on N (fc1: Ntiles=32, 4 n-tiles per XCD stay L2-resident)
// mode 1: contiguous tile range per XCD, n-inner (A panel shared within XCD)
template<int MT, int NT, int TM, int TN, int EPI>
__global__ __launch_bounds__(256, 4)
void gemm_kernel(const float* __restrict__ A, const float* __restrict__ Bt,
                 const float* __restrict__ bias, const float* __restrict__ latent,
                 const float* __restrict__ gain, float* __restrict__ C,
                 int M, int N, int K, int mode, int ntiles) {
  constexpr int ASR = MT + 4, BSR = NT + 4;
  __shared__ float As[32 * ASR];
  __shared__ float Bs[32 * BSR];
  int tid = threadIdx.x, tx = tid & 15, ty = tid >> 4;
  int bid = blockIdx.x;
  int m_idx, n_idx;
  if (mode == 0) {
    int xcd = bid & 7, w = bid >> 3;
    n_idx = xcd * 4 + (w & 3);
    m_idx = w >> 2;
  } else {
    int g8 = gridDim.x >> 3;
    int tile = (bid & 7) * g8 + (bid >> 3);
    m_idx = tile / ntiles;
    n_idx = tile - m_idx * ntiles;
  }
  int m0 = m_idx * MT, n0 = n_idx * NT;
  float acc[TM * TN];
#pragma unroll
  for (int i = 0; i < TM * TN; ++i) acc[i] = 0.f;
  const bool kal = (K & 3) == 0;

  for (int kt = 0; kt < K; kt += 32) {
    int klen = K - kt; if (klen > 32) klen = 32;   // klen % 4 == 0 for all our K
    // A stage: float4 along k, scatter to k-major LDS
#pragma unroll
    for (int rep = 0; rep < MT / 32; ++rep) {
      int idx = rep * 256 + tid;
      int m = idx >> 3, kq = (idx & 7) * 4;
      if (kq < klen) {
        const float* ap = A + (size_t)(m0 + m) * K + kt + kq;
        float v0, v1, v2, v3;
        if (kal) { v4f v = *(const v4f*)ap; v0 = v.x; v1 = v.y; v2 = v.z; v3 = v.w; }
        else { v0 = ap[0]; v1 = ap[1]; v2 = ap[2]; v3 = ap[3]; }
        As[(kq + 0) * ASR + m] = v0;
        As[(kq + 1) * ASR + m] = v1;
        As[(kq + 2) * ASR + m] = v2;
        As[(kq + 3) * ASR + m] = v3;
      }
    }
    // B stage: float4 along n, vector LDS write
#pragma unroll
    for (int rep = 0; rep < NT / 32; ++rep) {
      int idx = rep * 256 + tid;
      int kk = idx / (NT / 4), nq = (idx % (NT / 4)) * 4;
      if (kk < klen) {
        v4f v = *(const v4f*)(Bt + (size_t)(kt + kk) * N + n0 + nq);
        *(v4f*)&Bs[kk * BSR + nq] = v;
      }
    }
    __syncthreads();
#define GEMM_BODY(kk)                                                        \
    {                                                                        \
      float a[TM], b[TN];                                                    \
      _Pragma("unroll")                                                      \
      for (int i = 0; i < TM; i += 4)                                        \
        *(v4f*)&a[i] = *(const v4f*)&As[(kk) * ASR + ty * TM + i];           \
      _Pragma("unroll")                                                      \
      for (int i = 0; i < TN; i += 4)                                        \
        *(v4f*)&b[i] = *(const v4f*)&Bs[(kk) * BSR + tx * TN + i];           \
      _Pragma("unroll")                                                      \
      for (int j = 0; j < TM; ++j)                                           \
        _Pragma("unroll")                                                    \
        for (int d = 0; d < TN; ++d)                                         \
          acc[j * TN + d] = fmaf(a[j], b[d], acc[j * TN + d]);               \
    }
    if (klen == 32) {
#pragma unroll
      for (int kk = 0; kk < 32; ++kk) GEMM_BODY(kk)
    } else {
      for (int kk = 0; kk < klen; ++kk) GEMM_BODY(kk)
    }
#undef GEMM_BODY
    __syncthreads();
  }

  float bv[TN];
#pragma unroll
  for (int d = 0; d < TN; ++d) bv[d] = bias[n0 + tx * TN + d];
  float g = (EPI == 1) ? fabsf(gain[0]) : 0.f;
#pragma unroll
  for (int j = 0; j < TM; ++j) {
    int m = m0 + ty * TM + j;
    float o[TN];
    if (EPI == 0) {
#pragma unroll
      for (int d = 0; d < TN; ++d) o[d] = fmaxf(acc[j * TN + d] + bv[d], 0.0f);
    } else {
      float lat = latent[m % T];
#pragma unroll
      for (int d = 0; d < TN; ++d) {
        float v = acc[j * TN + d] + bv[d];
        float e = expf(-fabsf(v));
        float l = log1pf(e);
        float sp = fmaxf(v, 0.0f) + l;
        o[d] = (sp * lat) * g;
      }
    }
    float* cp = C + (size_t)m * N + n0 + tx * TN;
#pragma unroll
    for (int i = 0; i < TN; i += 4) {
      v4f v; v.x = o[i]; v.y = o[i + 1]; v.z = o[i + 2]; v.w = o[i + 3];
      __builtin_nontemporal_store(v, (v4f*)(cp + i));
    }
  }
}

// Fused spike sampling + decay-weighted reduction.
// spikes = [lam>0 && log(u1) > -lam]; u1 = partitionable threefry XOR-fold.
__global__ __launch_bounds__(256) void spike_weighted_kernel(float* __restrict__ out,
                                                             float* __restrict__ wt,
                                                             uint32_t k0, uint32_t k1) {
  __shared__ float dec[128];
  int tid = threadIdx.x;
  if (tid < T) {
    float step = 2.0f / 99.0f;
    float a = step * (float)tid;
    dec[tid] = expf(a - 2.0f);
  }
  __syncthreads();
  int b = blockIdx.x >> 4;
  int w = ((blockIdx.x & 15) << 8) + tid;
  float acc = 0.f;
  for (int t = 0; t < T; ++t) {
    uint32_t p = (uint32_t)((b * T + t) * WID + w);
    float lam = __builtin_nontemporal_load(&out[DRIVE_OFF + p]);
    uint32_t y0, y1;
    threefry2x32(k0, k1, 0u, p, y0, y1);
    uint32_t bits = y0 ^ y1;
    float u = __uint_as_float((bits >> 9) | 0x3f800000u) - 1.0f;
    float s = (lam > 0.0f && logf(u) > -lam) ? 1.0f : 0.0f;
    __builtin_nontemporal_store(s, &out[SPIKES_OFF + p]);
    acc = fmaf(s, dec[t], acc);
  }
  wt[b * WID + w] = acc;
}

// logits[b,c] = sum_w weighted[b,w]*W2q[c,w] + b2[c]
__global__ void logits_kernel(const float* __restrict__ wt,
                              const float* __restrict__ w2,
                              const float* __restrict__ b2,
                              float* __restrict__ out) {
  __shared__ float sm[256];
  int b = blockIdx.x / CLS, c = blockIdx.x - b * CLS;
  const float* wr = wt + (size_t)b * WID;
  const float* w2r = w2 + (size_t)c * WID;
  float p = 0.f;
  for (int w = threadIdx.x; w < WID; w += 256) p = fmaf(wr[w], w2r[w], p);
  sm[threadIdx.x] = p;
  __syncthreads();
  for (int s = 128; s > 0; s >>= 1) {
    if (threadIdx.x < s) sm[threadIdx.x] += sm[threadIdx.x + s];
    __syncthreads();
  }
  if (threadIdx.x == 0) out[LOGITS_OFF + blockIdx.x] = sm[0] + b2[c];
}

extern "C" void kernel_launch(void* const* d_in, const int* in_sizes, int n_in,
                              void* d_out, int out_size, void* d_ws, size_t ws_size,
                              hipStream_t stream) {
  (void)in_sizes; (void)n_in; (void)out_size; (void)ws_size;
  const float* x         = (const float*)d_in[0];
  const float* latent    = (const float*)d_in[1];
  const float* spatial_W = (const float*)d_in[2];
  const float* spatial_b = (const float*)d_in[3];
  const float* conv_W    = (const float*)d_in[4];
  const float* conv_b    = (const float*)d_in[5];
  const float* fc1_W     = (const float*)d_in[6];
  const float* fc1_b     = (const float*)d_in[7];
  const float* fc2_W     = (const float*)d_in[8];
  const float* fc2_b     = (const float*)d_in[9];
  const float* gain      = (const float*)d_in[10];
  float* out = (float*)d_out;
  uint32_t* wsu = (uint32_t*)d_ws;
  float* wsf = (float*)d_ws;
  float* S = out + SPIKES_OFF;   // scratch in the not-yet-written spikes region

  uint32_t sk0, sk1;
  threefry2x32(0u, 42u, 0u, 1u, sk0, sk1);

  (void)hipMemsetAsync(wsu + WS_SLOTS, 0, 3 * sizeof(uint32_t), stream);
  absmax_kernel<<<64, 256, 0, stream>>>(spatial_W, RED * IN_F, wsu + WS_SLOTS + 0);
  absmax_kernel<<<256, 256, 0, stream>>>(fc1_W, WID * RED, wsu + WS_SLOTS + 1);
  absmax_kernel<<<32, 256, 0, stream>>>(fc2_W, CLS * WID, wsu + WS_SLOTS + 2);

  // spatial_W [256][700] -> WST [700][256]
  quant_t_kernel<<<dim3(22, 8), 256, 0, stream>>>(spatial_W, S + SC_WST, RED, IN_F, wsu + WS_SLOTS + 0);
  // fc1_W [4096][256] -> W1T [256][4096]
  quant_t_kernel<<<dim3(8, 128), 256, 0, stream>>>(fc1_W, S + SC_W1T, WID, RED, wsu + WS_SLOTS + 1);
  quant_kernel<<<320, 256, 0, stream>>>(fc2_W, wsf + WS_W2Q, CLS * WID, wsu + WS_SLOTS + 2);
  convw_t_kernel<<<1280, 256, 0, stream>>>(conv_W, S + SC_CWT);

  // spatial: xp = relu(x @ WsqT + b)   M=6400 N=256 K=700, 100x4 tiles
  gemm_kernel<64, 64, 4, 4, 0><<<400, 256, 0, stream>>>(
      x, S + SC_WST, spatial_b, nullptr, nullptr, wsf + WS_XP, BT, RED, IN_F, 1, 4);

  im2col_kernel<<<32000, 256, 0, stream>>>(wsf + WS_XP, S + SC_IM2);

  // conv: co = relu(im2col @ cwt + cb)  M=6400 N=256 K=1280
  gemm_kernel<64, 64, 4, 4, 0><<<400, 256, 0, stream>>>(
      S + SC_IM2, S + SC_CWT, conv_b, nullptr, nullptr, wsf + WS_CO, BT, RED, 1280, 1, 4);

  // fc1: drive = softplus(co @ W1qT + b)*latent*|g|  M=6400 N=4096 K=256, 50x32 tiles
  gemm_kernel<128, 128, 8, 8, 1><<<1600, 256, 0, stream>>>(
      wsf + WS_CO, S + SC_W1T, fc1_b, latent, gain, out + DRIVE_OFF, BT, WID, RED, 0, 32);

  spike_weighted_kernel<<<B * 16, 256, 0, stream>>>(out, wsf + WS_WEIGHTED, sk0, sk1);

  logits_kernel<<<B * CLS, 256, 0, stream>>>(wsf + WS_WEIGHTED, wsf + WS_W2Q, fc2_b, out);
}